// Round 5
// baseline (349.723 us; speedup 1.0000x reference)
//
#include <hip/hip_runtime.h>
#include <hip/hip_bf16.h>
#include <stdint.h>

// EMASpitDelta: B=128, L=4096, H=64, V=64, HALF=32, ALPHA=0.95
// Gram-table backward scan, rank-4 blocked. State y[v] = k_v . z across 64
// lanes. Rounds 1/4 measured 74/90 cyc/step at VALUBusy 11-14%: the serial
// dependent cross-lane chain (readlane(tok)->readlane(y,svt)->fmac) appears
// to cost ~35-45cyc per dependent cross-lane hop on a lone wave. This round
// removes ALL runtime lane-selects from the chain:
//  - per 64-step group, ONE ds_bpermute gathers ry[lane] = y[v_lane];
//  - per 4-step block, a 4x4 unit-triangular solve in broadcast VGPRs
//    (C_xy = gv_x[v_y] extracted via compile-time-lane readlanes from
//    bpermute-gathered rows, prefetched one block ahead);
//  - cross-block corrections = 4 fmacs on ry per block (corrects all
//    later-processed = lower lanes; over-correction of consumed lanes is
//    harmless);
//  - y updated by 4 fmacs/block, consumed only at next group's bpermute.
// Chain per 4 steps: 4 independent const-lane readlanes + depth-3 fma
// solve + 4 fmacs ~= 12-17 cyc/step vs measured 90.

#define BETA 0.05f
#define NB 128
#define NL 4096

struct Ptrs { const void* p[15]; };
// p idx: 0=embed 1=W1 2=b1 3=W2 4=b2 5=gamma 6=beta 7=Ws 8=bs 9=We 10=be
//        11=Wrp 12=brp 13=Wout 14=bout

__device__ inline float readlane_f(float v, int l) {
    return __int_as_float(__builtin_amdgcn_readlane(__float_as_int(v), l));
}
__device__ inline float bperm_f(int idx, float v) {
    return __int_as_float(__builtin_amdgcn_ds_bpermute(idx, __float_as_int(v)));
}
__device__ inline float ldT(const float* p, int i) { return p[i]; }
__device__ inline float ldT(const __hip_bfloat16* p, int i) { return __bfloat162float(p[i]); }

// ---------------- Kernel 1: per-token-value tables (raw inputs) -----------
// grid 64 (token v), block 64 (feature j). tbl (f32):
// [0..2047]=hs, [2048..4095]=ks(norm), [4096..6143]=he, [6144..8191]=ke
template <typename T>
__device__ void build_tables_body(const T* emb, const T* W1, const T* b1,
                                  const T* W2, const T* b2, const T* gam,
                                  const T* bet, const T* Wsm, const T* bsv,
                                  const T* Wem, const T* bev, float* tbl)
{
    int v = blockIdx.x;
    int j = threadIdx.x;
    __shared__ float h0s[64];
    __shared__ float act[128];
    __shared__ float hrow[64];

    float h0 = ldT(emb, v * 64 + j);
    h0s[j] = h0;
    __syncthreads();

    float za = ldT(b1, j);
    float zb = ldT(b1, j + 64);
    for (int k = 0; k < 64; ++k) {
        float hk = h0s[k];
        za = fmaf(hk, ldT(W1, k * 128 + j), za);
        zb = fmaf(hk, ldT(W1, k * 128 + j + 64), zb);
    }
    act[j] = fmaxf(za, 0.0f);
    act[j + 64] = fmaxf(zb, 0.0f);
    __syncthreads();

    float ff = ldT(b2, j);
    for (int k = 0; k < 128; ++k)
        ff = fmaf(act[k], ldT(W2, k * 64 + j), ff);
    float x = h0 + ff;

    float s = x;
    for (int off = 32; off >= 1; off >>= 1) s += __shfl_xor(s, off, 64);
    float mu = s * (1.0f / 64.0f);
    float d = x - mu;
    float s2 = d * d;
    for (int off = 32; off >= 1; off >>= 1) s2 += __shfl_xor(s2, off, 64);
    float var = s2 * (1.0f / 64.0f);
    float h = d / sqrtf(var + 1e-5f) * ldT(gam, j) + ldT(bet, j);
    hrow[j] = h;
    __syncthreads();

    if (j < 32) {
        float sv = ldT(bsv, j);
        for (int k = 0; k < 64; ++k)
            sv = fmaf(hrow[k], ldT(Wsm, k * 32 + j), sv);
        float n2 = sv * sv;
        for (int off = 16; off >= 1; off >>= 1) n2 += __shfl_xor(n2, off, 64);
        float nrm = fmaxf(sqrtf(n2), 1e-12f);
        tbl[v * 32 + j] = sv;
        tbl[2048 + v * 32 + j] = sv / nrm;
    } else {
        int jj = j - 32;
        float ev = ldT(bev, jj);
        for (int k = 0; k < 64; ++k)
            ev = fmaf(hrow[k], ldT(Wem, k * 32 + jj), ev);
        float n2 = ev * ev;
        for (int off = 16; off >= 1; off >>= 1) n2 += __shfl_xor(n2, off, 64);
        float nrm = fmaxf(sqrtf(n2), 1e-12f);
        tbl[4096 + v * 32 + jj] = ev;
        tbl[6144 + v * 32 + jj] = ev / nrm;
    }
}

__global__ __launch_bounds__(64, 2) void build_tables(Ptrs ps, float* __restrict__ tbl)
{
    uint32_t g0 = *(const uint32_t*)ps.p[5];
    if (g0 == 0x3F803F80u)
        build_tables_body((const __hip_bfloat16*)ps.p[0], (const __hip_bfloat16*)ps.p[1],
                          (const __hip_bfloat16*)ps.p[2], (const __hip_bfloat16*)ps.p[3],
                          (const __hip_bfloat16*)ps.p[4], (const __hip_bfloat16*)ps.p[5],
                          (const __hip_bfloat16*)ps.p[6], (const __hip_bfloat16*)ps.p[7],
                          (const __hip_bfloat16*)ps.p[8], (const __hip_bfloat16*)ps.p[9],
                          (const __hip_bfloat16*)ps.p[10], tbl);
    else
        build_tables_body((const float*)ps.p[0], (const float*)ps.p[1],
                          (const float*)ps.p[2], (const float*)ps.p[3],
                          (const float*)ps.p[4], (const float*)ps.p[5],
                          (const float*)ps.p[6], (const float*)ps.p[7],
                          (const float*)ps.p[8], (const float*)ps.p[9],
                          (const float*)ps.p[10], tbl);
}

// ---------------- Kernel 2: fused gram + scan + readout -------------------
template <int MAT>
__device__ inline float mk_tf(int g, int lane) {
    int t1 = g * 64 + lane + 1;
    float f = MAT ? (float)t1 : 1.0f;
    return (t1 == NL) ? 0.0f : f;   // mask nonexistent step t = 4095
}

// Prefetch block K (steps = lanes 63-4K .. 60-4K, descending t):
//  gv[P][i] = -b_t * G[v_t][lane]  (row, per-lane)
//  gt[P][i] = gv[P][i] gathered at v_lane positions (bpermute)
//  cXY[P]   = gv_X[v_Y] cross coefficients (const-lane readlanes of gt)
#define LOAD4(P, K)                                                        \
    {                                                                      \
        const int La_ = 63 - 4 * (K);                                      \
        int va_ = __builtin_amdgcn_readlane(tokc, La_);                    \
        int vb_ = __builtin_amdgcn_readlane(tokc, La_ - 1);                \
        int vc_ = __builtin_amdgcn_readlane(tokc, La_ - 2);                \
        int vd_ = __builtin_amdgcn_readlane(tokc, La_ - 3);                \
        float a_ = GlM[va_ * 64 + lane];                                   \
        float b_ = GlM[vb_ * 64 + lane];                                   \
        float c_ = GlM[vc_ * 64 + lane];                                   \
        float d_ = GlM[vd_ * 64 + lane];                                   \
        if (MAT) {                                                         \
            a_ *= readlane_f(tfc, La_);                                    \
            b_ *= readlane_f(tfc, La_ - 1);                                \
            c_ *= readlane_f(tfc, La_ - 2);                                \
            d_ *= readlane_f(tfc, La_ - 3);                                \
        }                                                                  \
        if (!MAT && (K) == 0 && g == 63) a_ = 0.0f;  /* t=4095 mask */     \
        gv[P][0] = a_; gv[P][1] = b_; gv[P][2] = c_; gv[P][3] = d_;        \
        gt[P][0] = bperm_f(idx, a_);                                       \
        gt[P][1] = bperm_f(idx, b_);                                       \
        gt[P][2] = bperm_f(idx, c_);                                       \
        gt[P][3] = bperm_f(idx, d_);                                       \
        c01[P] = readlane_f(gt[P][0], La_ - 1);                            \
        c02[P] = readlane_f(gt[P][0], La_ - 2);                            \
        c03[P] = readlane_f(gt[P][0], La_ - 3);                            \
        c12[P] = readlane_f(gt[P][1], La_ - 2);                            \
        c13[P] = readlane_f(gt[P][1], La_ - 3);                            \
        c23[P] = readlane_f(gt[P][2], La_ - 3);                            \
    }

// Chain block K: 4 independent const-lane readlanes of ry, 4x4 triangular
// solve in broadcast regs, correct ry (later lanes) + fold y + capture s.
#define CHAIN4(P, K)                                                       \
    {                                                                      \
        const int La_ = 63 - 4 * (K);                                      \
        float ra_ = readlane_f(ry, La_);                                   \
        float rb_ = readlane_f(ry, La_ - 1);                               \
        float rc_ = readlane_f(ry, La_ - 2);                               \
        float rd_ = readlane_f(ry, La_ - 3);                               \
        float sA_ = ra_;                                                   \
        float sB_ = fmaf(sA_, c01[P], rb_);                                \
        float sC_ = fmaf(sB_, c12[P], fmaf(sA_, c02[P], rc_));             \
        float sD_ = fmaf(sC_, c23[P], fmaf(sB_, c13[P],                    \
                          fmaf(sA_, c03[P], rd_)));                        \
        ry = fmaf(sA_, gt[P][0], ry);                                      \
        ry = fmaf(sB_, gt[P][1], ry);                                      \
        ry = fmaf(sC_, gt[P][2], ry);                                      \
        ry = fmaf(sD_, gt[P][3], ry);                                      \
        y = fmaf(sA_, gv[P][0], y);                                        \
        y = fmaf(sB_, gv[P][1], y);                                        \
        y = fmaf(sC_, gv[P][2], y);                                        \
        y = fmaf(sD_, gv[P][3], y);                                        \
        csave = (lane == La_) ? sA_ : csave;                               \
        csave = (lane == La_ - 1) ? sB_ : csave;                           \
        csave = (lane == La_ - 2) ? sC_ : csave;                           \
        csave = (lane == La_ - 3) ? sD_ : csave;                           \
    }

template <int MAT>
__device__ void scan_loop(const int* __restrict__ sb, const float* GlM,
                          float* da, float y, int lane, float bfac)
{
    float csave = 0.0f;
    int tokc = sb[63 * 64 + lane];
    float tfc = mk_tf<MAT>(63, lane);

#pragma unroll 1
    for (int g = 63; g >= 0; --g) {
        int tokn = 0; float tfn = 0.0f;
        if (g > 0) { tokn = sb[(g - 1) * 64 + lane]; tfn = mk_tf<MAT>(g - 1, lane); }
        int idx = tokc << 2;
        // ry[lane] = y[v_lane] snapshot for the whole group (one gather).
        float ry = bperm_f(idx, y);

        float gv[2][4], gt[2][4];
        float c01[2], c02[2], c03[2], c12[2], c13[2], c23[2];

        LOAD4(0, 0)
#pragma unroll
        for (int k = 0; k < 16; ++k) {
            if (k < 15) {
                if ((k & 1) == 0) LOAD4(1, k + 1)
                else              LOAD4(0, k + 1)
            }
            asm volatile("" ::: "memory");
            if ((k & 1) == 0) CHAIN4(0, k)
            else              CHAIN4(1, k)
        }

        // d_t = b_t * s_t ; lane t holds s_t ; b_t = bfac * tf_t
        // (MAT0: tf=1 except t=4095 -> 0, masking the padded step's dv).
        float dv = csave * (bfac * tfc);
        atomicAdd(&da[tokc], dv);
        tokc = tokn; tfc = tfn;
    }
}

// grid NB blocks (one per batch), 128 threads = 2 waves (wave = mat).
__global__ __launch_bounds__(128, 1) void ema_scan_fused(
    const int* __restrict__ seq, const float* __restrict__ tbl,
    Ptrs ps, void* __restrict__ outv)
{
    __shared__ float Gl[2 * 4096];      // [mat][vt][v], pre-scaled by -bfac
    __shared__ float K[2 * 64 * 36];    // ks rows, 36-pad (conflict-free b128)
    __shared__ float daL[128];
    __shared__ float rv[64];
    __shared__ float o1s[64];

    int b = blockIdx.x;
    int tid = threadIdx.x;
    int mat = tid >> 6;
    int lane = tid & 63;

    daL[tid] = 0.0f;                    // own-wave range, no barrier needed

    // ---- stage normalized k table for this mat (wave-local) ----
    const float4* ksrc = (const float4*)(tbl + 2048 + mat * 4096);
    float* Km = K + mat * 64 * 36;
    for (int i = lane; i < 512; i += 64) {
        float4 kv = ksrc[i];
        int vv = i >> 3, j = (i & 7) * 4;
        float* kd = Km + vv * 36 + j;
        kd[0] = kv.x; kd[1] = kv.y; kd[2] = kv.z; kd[3] = kv.w;
    }

    float Kown[32];
    {
        const float4* kr = (const float4*)(Km + lane * 36);
#pragma unroll
        for (int j = 0; j < 8; ++j) {
            float4 t = kr[j];
            Kown[4 * j + 0] = t.x; Kown[4 * j + 1] = t.y;
            Kown[4 * j + 2] = t.z; Kown[4 * j + 3] = t.w;
        }
    }

    const int* sb = seq + (size_t)b * NL;
    int vlast = sb[NL - 1];
    float bfac = mat ? (BETA / 4096.0f) : BETA;
    float* GlM = Gl + mat * 4096;

    // ---- gram: G[vt][lane] = k_vt . k_lane ; store -bfac*G; grab y row ---
    float y = 0.0f;
#pragma unroll 2
    for (int vt = 0; vt < 64; ++vt) {
        const float4* rr = (const float4*)(Km + vt * 36);   // uniform: bcast
        float acc = 0.0f;
#pragma unroll
        for (int j = 0; j < 8; ++j) {
            float4 t = rr[j];
            acc = fmaf(t.x, Kown[4 * j + 0], acc);
            acc = fmaf(t.y, Kown[4 * j + 1], acc);
            acc = fmaf(t.z, Kown[4 * j + 2], acc);
            acc = fmaf(t.w, Kown[4 * j + 3], acc);
        }
        GlM[vt * 64 + lane] = acc * (-bfac);
        if (vt == vlast) y = acc;       // y init = G_raw[vlast][lane]
    }

    // ---- backward scan (rank-4 blocked; MAT0 skips per-step tf) ---------
    if (mat == 0) scan_loop<0>(sb, GlM, daL, y, lane, BETA);
    else          scan_loop<1>(sb, GlM, daL + 64, y, lane, BETA / 4096.0f);

    __syncthreads();                    // both mats' daL complete

    // ---- readout: r = H^T da ; out = (r @ Wrp + brp) @ Wout + bout -------
    if (tid < 64) {
        int half = tid >> 5;            // 0: rs, 1: re
        int j = tid & 31;
        const float* hsrc = tbl + half * 4096;   // hs | he (unnormalized)
        const float* dv = daL + half * 64;
        float r = 0.0f;
        for (int v = 0; v < 64; ++v)
            r = fmaf(dv[v], hsrc[v * 32 + j], r);
        rv[tid] = r;
    }
    __syncthreads();

    uint32_t g0h = *(const uint32_t*)ps.p[5];
    int isbf = (g0h == 0x3F803F80u) ? 1 : 0;
    if (tid < 64) {
        float o;
        if (isbf) {
            const __hip_bfloat16* W = (const __hip_bfloat16*)ps.p[11];
            o = __bfloat162float(((const __hip_bfloat16*)ps.p[12])[tid]);
            for (int i = 0; i < 64; ++i)
                o = fmaf(rv[i], __bfloat162float(W[i * 64 + tid]), o);
        } else {
            const float* W = (const float*)ps.p[11];
            o = ((const float*)ps.p[12])[tid];
            for (int i = 0; i < 64; ++i)
                o = fmaf(rv[i], W[i * 64 + tid], o);
        }
        o1s[tid] = o;
    }
    __syncthreads();
    if (tid < 64) {
        float o2;
        if (isbf) {
            const __hip_bfloat16* W = (const __hip_bfloat16*)ps.p[13];
            o2 = __bfloat162float(((const __hip_bfloat16*)ps.p[14])[tid]);
            for (int i = 0; i < 64; ++i)
                o2 = fmaf(o1s[i], __bfloat162float(W[i * 64 + tid]), o2);
            ((__hip_bfloat16*)outv)[b * 64 + tid] = __float2bfloat16(o2);
        } else {
            const float* W = (const float*)ps.p[13];
            o2 = ((const float*)ps.p[14])[tid];
            for (int i = 0; i < 64; ++i)
                o2 = fmaf(o1s[i], W[i * 64 + tid], o2);
            ((float*)outv)[b * 64 + tid] = o2;
        }
    }
}

extern "C" void kernel_launch(void* const* d_in, const int* in_sizes, int n_in,
                              void* d_out, int out_size, void* d_ws, size_t ws_size,
                              hipStream_t stream) {
    const int* seq = (const int*)d_in[0];
    Ptrs ps;
    for (int i = 0; i < 15; ++i) ps.p[i] = d_in[i + 1];

    // ws (floats): tbl[8192]
    float* tbl = (float*)d_ws;

    build_tables<<<64, 64, 0, stream>>>(ps, tbl);
    ema_scan_fused<<<NB, 128, 0, stream>>>(seq, tbl, ps, d_out);
}

// Round 6
// 244.958 us; speedup vs baseline: 1.4277x; 1.4277x over previous
//
#include <hip/hip_runtime.h>
#include <hip/hip_bf16.h>
#include <stdint.h>

// EMASpitDelta: B=128, L=4096, H=64, V=64, HALF=32, ALPHA=0.95
// Chunked Gram-space backward scan. R1/R4/R5 showed a lone wave's serial
// readlane->fmac chain costs 74-154 cyc/step regardless of prefetching --
// so this round removes the long chain: T=32 chunks; per chunk the true
// step coefficients are s = (I-C)^-1 ry with C[p][j] = -b_j G[v_p][v_j]
// (pure Gram lookups) and ry = bpermute(y) at chunk entry. V=(I-C)^-1 is
// built column-per-lane by 7 throughput-bound build waves (static-unrolled
// 496 fma + 496 const-lane readlanes, R0's proven 78%-VALUBusy regime);
// one fold wave consumes V: per chunk 1 bpermute + 32-fma solve + 32 row
// fmas on y (plain matvec, no dependent cross-lane chain). Producer/
// consumer via 14 double-buffered LDS slots + 1 barrier/round, 20 rounds.
// d = s*b -> per-lane LDS atomicAdd; readout fused cross-block via
// agent-scope atomics (2 launches total).

#define BETA 0.05f
#define NB 128
#define NL 4096
#define TC 32            // chunk length
#define NCH 128          // chunks per (b,mat)
#define SLOT_F 1088      // V[32*33]=1056 + tok[32]
#define NSLOT 14         // 2 x 7 (double-buffered)

// shared layout (floats)
#define L_GR   (NSLOT * SLOT_F)          // 15232: Graw[64][64]
#define L_DA   (L_GR + 4096)             // daL[64]
#define L_RV   (L_DA + 64)               // rv[64]
#define L_O1   (L_RV + 64)               // o1s[64]
#define L_WHO  (L_O1 + 64)               // int who
#define L_TOT  (L_WHO + 4)

struct Ptrs { const void* p[15]; };
// p idx: 0=embed 1=W1 2=b1 3=W2 4=b2 5=gamma 6=beta 7=Ws 8=bs 9=We 10=be
//        11=Wrp 12=brp 13=Wout 14=bout

__device__ inline float readlane_f(float v, int l) {
    return __int_as_float(__builtin_amdgcn_readlane(__float_as_int(v), l));
}
__device__ inline float bperm_f(int idx, float v) {
    return __int_as_float(__builtin_amdgcn_ds_bpermute(idx, __float_as_int(v)));
}
__device__ inline float ldT(const float* p, int i) { return p[i]; }
__device__ inline float ldT(const __hip_bfloat16* p, int i) { return __bfloat162float(p[i]); }

// ---------------- Kernel 1: per-token-value tables (raw inputs) -----------
// grid 64 (token v), block 64 (feature j). tbl (f32):
// [0..2047]=hs, [2048..4095]=ks(norm), [4096..6143]=he, [6144..8191]=ke
template <typename T>
__device__ void build_tables_body(const T* emb, const T* W1, const T* b1,
                                  const T* W2, const T* b2, const T* gam,
                                  const T* bet, const T* Wsm, const T* bsv,
                                  const T* Wem, const T* bev, float* tbl)
{
    int v = blockIdx.x;
    int j = threadIdx.x;
    __shared__ float h0s[64];
    __shared__ float act[128];
    __shared__ float hrow[64];

    float h0 = ldT(emb, v * 64 + j);
    h0s[j] = h0;
    __syncthreads();

    float za = ldT(b1, j);
    float zb = ldT(b1, j + 64);
    for (int k = 0; k < 64; ++k) {
        float hk = h0s[k];
        za = fmaf(hk, ldT(W1, k * 128 + j), za);
        zb = fmaf(hk, ldT(W1, k * 128 + j + 64), zb);
    }
    act[j] = fmaxf(za, 0.0f);
    act[j + 64] = fmaxf(zb, 0.0f);
    __syncthreads();

    float ff = ldT(b2, j);
    for (int k = 0; k < 128; ++k)
        ff = fmaf(act[k], ldT(W2, k * 64 + j), ff);
    float x = h0 + ff;

    float s = x;
    for (int off = 32; off >= 1; off >>= 1) s += __shfl_xor(s, off, 64);
    float mu = s * (1.0f / 64.0f);
    float d = x - mu;
    float s2 = d * d;
    for (int off = 32; off >= 1; off >>= 1) s2 += __shfl_xor(s2, off, 64);
    float var = s2 * (1.0f / 64.0f);
    float h = d / sqrtf(var + 1e-5f) * ldT(gam, j) + ldT(bet, j);
    hrow[j] = h;
    __syncthreads();

    if (j < 32) {
        float sv = ldT(bsv, j);
        for (int k = 0; k < 64; ++k)
            sv = fmaf(hrow[k], ldT(Wsm, k * 32 + j), sv);
        float n2 = sv * sv;
        for (int off = 16; off >= 1; off >>= 1) n2 += __shfl_xor(n2, off, 64);
        float nrm = fmaxf(sqrtf(n2), 1e-12f);
        tbl[v * 32 + j] = sv;
        tbl[2048 + v * 32 + j] = sv / nrm;
    } else {
        int jj = j - 32;
        float ev = ldT(bev, jj);
        for (int k = 0; k < 64; ++k)
            ev = fmaf(hrow[k], ldT(Wem, k * 32 + jj), ev);
        float n2 = ev * ev;
        for (int off = 16; off >= 1; off >>= 1) n2 += __shfl_xor(n2, off, 64);
        float nrm = fmaxf(sqrtf(n2), 1e-12f);
        tbl[4096 + v * 32 + jj] = ev;
        tbl[6144 + v * 32 + jj] = ev / nrm;
    }
}

__global__ __launch_bounds__(64, 2) void build_tables(Ptrs ps, float* __restrict__ tbl,
                                                      int* __restrict__ flags)
{
    if (blockIdx.x == 0) {              // re-zero pair flags every launch
        flags[threadIdx.x] = 0;
        flags[threadIdx.x + 64] = 0;
    }
    uint32_t g0 = *(const uint32_t*)ps.p[5];
    if (g0 == 0x3F803F80u)
        build_tables_body((const __hip_bfloat16*)ps.p[0], (const __hip_bfloat16*)ps.p[1],
                          (const __hip_bfloat16*)ps.p[2], (const __hip_bfloat16*)ps.p[3],
                          (const __hip_bfloat16*)ps.p[4], (const __hip_bfloat16*)ps.p[5],
                          (const __hip_bfloat16*)ps.p[6], (const __hip_bfloat16*)ps.p[7],
                          (const __hip_bfloat16*)ps.p[8], (const __hip_bfloat16*)ps.p[9],
                          (const __hip_bfloat16*)ps.p[10], tbl);
    else
        build_tables_body((const float*)ps.p[0], (const float*)ps.p[1],
                          (const float*)ps.p[2], (const float*)ps.p[3],
                          (const float*)ps.p[4], (const float*)ps.p[5],
                          (const float*)ps.p[6], (const float*)ps.p[7],
                          (const float*)ps.p[8], (const float*)ps.p[9],
                          (const float*)ps.p[10], tbl);
}

// ---------------- Kernel 2: chunked scan, producer/consumer ---------------
// grid NB*2 (one block per (b,mat)), 512 threads = 8 waves.
// wave 0 = fold; waves 1..7 = V builders (7 chunks/round, 19 build rounds).
__global__ __launch_bounds__(512, 1) void ema_ms(
    const int* __restrict__ seq, const float* __restrict__ tbl,
    Ptrs ps, float* __restrict__ rvbuf, int* __restrict__ flags,
    void* __restrict__ outv)
{
    __shared__ float S[L_TOT];

    int bm = blockIdx.x;
    int b = bm >> 1, mat = bm & 1;
    int tid = threadIdx.x;
    int wid = tid >> 6, lane = tid & 63;
    const float bstep = BETA / 4096.0f;

    if (tid < 64) S[L_DA + tid] = 0.0f;

    // ---- prologue: stage K (aliased into slot area), compute Graw --------
    const float* ktab = tbl + 2048 + mat * 4096;
    for (int i = tid; i < 2048; i += 512)
        S[(i >> 5) * 33 + (i & 31)] = ktab[i];
    __syncthreads();

    {
        float Kown[32];
#pragma unroll
        for (int j = 0; j < 32; ++j) Kown[j] = S[lane * 33 + j];
        for (int v8 = 0; v8 < 8; ++v8) {
            int vt = wid * 8 + v8;
            float acc = 0.0f;
#pragma unroll
            for (int j = 0; j < 32; ++j)
                acc = fmaf(S[vt * 33 + j], Kown[j], acc);
            S[L_GR + vt * 64 + lane] = acc;     // raw Gram (symmetric)
        }
    }
    __syncthreads();

    const int* sb = seq + (size_t)b * NL;
    float y = 0.0f;
    if (wid == 0) {
        int vlast = sb[NL - 1];
        y = S[L_GR + vlast * 64 + lane];        // y[v] = k_v . q
    }

    // ---- rounds ----------------------------------------------------------
    for (int r = 0; r <= 19; ++r) {
        if (wid >= 1) {
            // ---------------- builder: V = (I-C)^-1 for one chunk ---------
            int ci = 7 * r + (wid - 1);
            if (r <= 18 && ci < NCH) {
                int c = NCH - 1 - ci;
                float* slot = S + ((r & 1) * 7 + (wid - 1)) * SLOT_F;
                int t = c * TC + 31 - lane;     // lane<32 meaningful
                int tok = 0; float bneg = 0.0f;
                if (lane < 32) {
                    tok = sb[t];
                    float bb = mat ? bstep * (float)(t + 1) : BETA;
                    if (t == NL - 1) bb = 0.0f;
                    bneg = -bb;
                    ((int*)(slot + 1056))[lane] = tok;
                }
                // grow[p][lane j] = -b_j * G[v_p][v_j]  (Gram symmetric)
                float grow[32];
#pragma unroll
                for (int p = 0; p < 32; ++p) {
                    int vp = __builtin_amdgcn_readlane(tok, p);
                    grow[p] = S[L_GR + vp * 64 + tok] * bneg;
                }
                // column-per-lane forward substitution (static unroll)
                float x[32];
                x[0] = (lane == 0) ? 1.0f : 0.0f;
#pragma unroll
                for (int p = 1; p < 32; ++p) {
                    float xp = (lane == p) ? 1.0f : 0.0f;
#pragma unroll
                    for (int j = 0; j < p; ++j)
                        xp = fmaf(readlane_f(grow[p], j), x[j], xp);
                    x[p] = xp;
                }
                if (lane < 32) {
#pragma unroll
                    for (int p = 0; p < 32; ++p)
                        slot[p * 33 + lane] = x[p];   // V[p][q], bank-safe
                }
            }
        } else {
            // ---------------- fold wave: consume previous round -----------
            if (r >= 1) {
                for (int w2 = 0; w2 < 7; ++w2) {
                    int ci = 7 * (r - 1) + w2;
                    if (ci >= NCH) break;
                    int c = NCH - 1 - ci;
                    float* slot = S + (((r - 1) & 1) * 7 + w2) * SLOT_F;
                    int tokf = (lane < 32) ? ((int*)(slot + 1056))[lane] : 0;
                    int t = c * TC + 31 - lane;
                    float bv = 0.0f;
                    if (lane < 32) {
                        float bb = mat ? bstep * (float)(t + 1) : BETA;
                        if (t == NL - 1) bb = 0.0f;
                        bv = bb;
                    }
                    float ry = bperm_f(tokf << 2, y);    // ry_p = y_in[v_p]
                    float vrow[32];
#pragma unroll
                    for (int q = 0; q < 32; ++q)
                        vrow[q] = slot[(lane & 31) * 33 + q];
                    float growf[32];
#pragma unroll
                    for (int p = 0; p < 32; ++p) {
                        int vp = __builtin_amdgcn_readlane(tokf, p);
                        growf[p] = S[L_GR + vp * 64 + lane];
                    }
                    // s = V ry (plain matvec, 4 partial chains)
                    float s0 = 0.f, s1 = 0.f, s2 = 0.f, s3 = 0.f;
#pragma unroll
                    for (int q = 0; q < 32; q += 4) {
                        s0 = fmaf(vrow[q + 0], readlane_f(ry, q + 0), s0);
                        s1 = fmaf(vrow[q + 1], readlane_f(ry, q + 1), s1);
                        s2 = fmaf(vrow[q + 2], readlane_f(ry, q + 2), s2);
                        s3 = fmaf(vrow[q + 3], readlane_f(ry, q + 3), s3);
                    }
                    float dv = ((s0 + s1) + (s2 + s3)) * bv;   // d_p = b_p s_p
                    if (lane < 32) atomicAdd(&S[L_DA + tokf], dv);
                    // y -= sum_p d_p * G[v_p][:]
                    float ya = 0.0f, yb = 0.0f;
#pragma unroll
                    for (int p = 0; p < 32; p += 2) {
                        ya = fmaf(-readlane_f(dv, p), growf[p], ya);
                        yb = fmaf(-readlane_f(dv, p + 1), growf[p + 1], yb);
                    }
                    y += ya + yb;
                }
            }
        }
        __syncthreads();
    }

    // ---- r-half = H^T da, publish, pair handshake ------------------------
    if (tid < 32) {
        float rr = 0.0f;
        const float* hsrc = tbl + mat * 4096;   // hs | he (unnormalized)
        for (int v = 0; v < 64; ++v)
            rr = fmaf(S[L_DA + v], hsrc[v * 32 + tid], rr);
        __hip_atomic_store(&rvbuf[bm * 32 + tid], rr,
                           __ATOMIC_RELAXED, __HIP_MEMORY_SCOPE_AGENT);
    }
    __syncthreads();
    if (tid == 0) {
        int old = __hip_atomic_fetch_add(&flags[b], 1,
                                         __ATOMIC_ACQ_REL, __HIP_MEMORY_SCOPE_AGENT);
        ((int*)S)[L_WHO] = old;
    }
    __syncthreads();
    if (((int*)S)[L_WHO] != 1) return;          // first finisher exits

    // ---- final readout for batch b (both halves now visible) -------------
    if (tid < 64)
        S[L_RV + tid] = __hip_atomic_load(&rvbuf[b * 64 + tid],
                                          __ATOMIC_RELAXED, __HIP_MEMORY_SCOPE_AGENT);
    __syncthreads();

    uint32_t g0h = *(const uint32_t*)ps.p[5];
    int isbf = (g0h == 0x3F803F80u) ? 1 : 0;
    if (tid < 64) {
        float o;
        if (isbf) {
            const __hip_bfloat16* W = (const __hip_bfloat16*)ps.p[11];
            o = __bfloat162float(((const __hip_bfloat16*)ps.p[12])[tid]);
            for (int i = 0; i < 64; ++i)
                o = fmaf(S[L_RV + i], __bfloat162float(W[i * 64 + tid]), o);
        } else {
            const float* W = (const float*)ps.p[11];
            o = ((const float*)ps.p[12])[tid];
            for (int i = 0; i < 64; ++i)
                o = fmaf(S[L_RV + i], W[i * 64 + tid], o);
        }
        S[L_O1 + tid] = o;
    }
    __syncthreads();
    if (tid < 64) {
        float o2;
        if (isbf) {
            const __hip_bfloat16* W = (const __hip_bfloat16*)ps.p[13];
            o2 = __bfloat162float(((const __hip_bfloat16*)ps.p[14])[tid]);
            for (int i = 0; i < 64; ++i)
                o2 = fmaf(S[L_O1 + i], __bfloat162float(W[i * 64 + tid]), o2);
            ((__hip_bfloat16*)outv)[b * 64 + tid] = __float2bfloat16(o2);
        } else {
            const float* W = (const float*)ps.p[13];
            o2 = ((const float*)ps.p[14])[tid];
            for (int i = 0; i < 64; ++i)
                o2 = fmaf(S[L_O1 + i], W[i * 64 + tid], o2);
            ((float*)outv)[b * 64 + tid] = o2;
        }
    }
}

extern "C" void kernel_launch(void* const* d_in, const int* in_sizes, int n_in,
                              void* d_out, int out_size, void* d_ws, size_t ws_size,
                              hipStream_t stream) {
    const int* seq = (const int*)d_in[0];
    Ptrs ps;
    for (int i = 0; i < 15; ++i) ps.p[i] = d_in[i + 1];

    // ws (floats): tbl[8192] | rvbuf[8192] | flags[128 ints]
    float* tbl = (float*)d_ws;
    float* rvbuf = tbl + 8192;
    int* flags = (int*)(rvbuf + 8192);

    build_tables<<<64, 64, 0, stream>>>(ps, tbl, flags);
    ema_ms<<<NB * 2, 512, 0, stream>>>(seq, tbl, ps, rvbuf, flags, d_out);
}

// Round 7
// 200.022 us; speedup vs baseline: 1.7484x; 1.2247x over previous
//
#include <hip/hip_runtime.h>
#include <hip/hip_bf16.h>
#include <stdint.h>

// EMASpitDelta: B=128, L=4096, H=64, V=64, HALF=32, ALPHA=0.95
// Chunked Gram-space backward scan (R6 structure), fixed:
//  - T=16 (builder arrays garr[16]+x[16]=32 regs -> no spill; R6's T=32
//    needed 64 array regs at VGPR_Count=64 -> scratch spill, 3x inst bloat,
//    FETCH_SIZE 1.45->2.44MB).
//  - __launch_bounds__(512,2): VGPR cap 256 (1 block/CU is all we need).
//  - builders pre-stage full G rows (grows[p][64], stride-1) so the fold's
//    y-update is conflict-free b32 reads, not token-gathers.
//  - V rows padded to 20 floats -> fold reads V via 4x ds_read_b128.
//  - 6 builder waves + wave 4 idle: fold wave 0 gets SIMD0's issue slots
//    to itself (waves map i%4).
// Per chunk: s = (I-C)^-1 ry, C_pj = -b_j G[v_p][v_j]; V built by forward
// substitution column-per-lane (parallel waves); fold: ry=bperm(y), s=V ry,
// d=b*s, da[v_p]+=d_p, y -= sum_p d_p G[v_p][:]. 2 launches.

#define BETA 0.05f
#define NB 128
#define NL 4096
#define TC 16            // chunk length
#define NCH 256          // chunks per (b,mat)
#define NBLD 6           // builder waves
#define SLOT_F 1360      // V[16][20]=320 | grows[16][64]=1024 | tok[16]
#define NSLOT 12         // 2 x 6 double-buffered

// shared layout (floats)
#define L_GR   (NSLOT * SLOT_F)          // 16320: Graw[64][64]
#define L_DA   (L_GR + 4096)             // daL[64]
#define L_RV   (L_DA + 64)
#define L_O1   (L_RV + 64)
#define L_WHO  (L_O1 + 64)
#define L_TOT  (L_WHO + 1)

struct Ptrs { const void* p[15]; };
// p idx: 0=embed 1=W1 2=b1 3=W2 4=b2 5=gamma 6=beta 7=Ws 8=bs 9=We 10=be
//        11=Wrp 12=brp 13=Wout 14=bout

__device__ inline float readlane_f(float v, int l) {
    return __int_as_float(__builtin_amdgcn_readlane(__float_as_int(v), l));
}
__device__ inline float bperm_f(int idx, float v) {
    return __int_as_float(__builtin_amdgcn_ds_bpermute(idx, __float_as_int(v)));
}
__device__ inline float ldT(const float* p, int i) { return p[i]; }
__device__ inline float ldT(const __hip_bfloat16* p, int i) { return __bfloat162float(p[i]); }

// ---------------- Kernel 1: per-token-value tables (raw inputs) -----------
template <typename T>
__device__ void build_tables_body(const T* emb, const T* W1, const T* b1,
                                  const T* W2, const T* b2, const T* gam,
                                  const T* bet, const T* Wsm, const T* bsv,
                                  const T* Wem, const T* bev, float* tbl)
{
    int v = blockIdx.x;
    int j = threadIdx.x;
    __shared__ float h0s[64];
    __shared__ float act[128];
    __shared__ float hrow[64];

    float h0 = ldT(emb, v * 64 + j);
    h0s[j] = h0;
    __syncthreads();

    float za = ldT(b1, j);
    float zb = ldT(b1, j + 64);
    for (int k = 0; k < 64; ++k) {
        float hk = h0s[k];
        za = fmaf(hk, ldT(W1, k * 128 + j), za);
        zb = fmaf(hk, ldT(W1, k * 128 + j + 64), zb);
    }
    act[j] = fmaxf(za, 0.0f);
    act[j + 64] = fmaxf(zb, 0.0f);
    __syncthreads();

    float ff = ldT(b2, j);
    for (int k = 0; k < 128; ++k)
        ff = fmaf(act[k], ldT(W2, k * 64 + j), ff);
    float x = h0 + ff;

    float s = x;
    for (int off = 32; off >= 1; off >>= 1) s += __shfl_xor(s, off, 64);
    float mu = s * (1.0f / 64.0f);
    float d = x - mu;
    float s2 = d * d;
    for (int off = 32; off >= 1; off >>= 1) s2 += __shfl_xor(s2, off, 64);
    float var = s2 * (1.0f / 64.0f);
    float h = d / sqrtf(var + 1e-5f) * ldT(gam, j) + ldT(bet, j);
    hrow[j] = h;
    __syncthreads();

    if (j < 32) {
        float sv = ldT(bsv, j);
        for (int k = 0; k < 64; ++k)
            sv = fmaf(hrow[k], ldT(Wsm, k * 32 + j), sv);
        float n2 = sv * sv;
        for (int off = 16; off >= 1; off >>= 1) n2 += __shfl_xor(n2, off, 64);
        float nrm = fmaxf(sqrtf(n2), 1e-12f);
        tbl[v * 32 + j] = sv;
        tbl[2048 + v * 32 + j] = sv / nrm;
    } else {
        int jj = j - 32;
        float ev = ldT(bev, jj);
        for (int k = 0; k < 64; ++k)
            ev = fmaf(hrow[k], ldT(Wem, k * 32 + jj), ev);
        float n2 = ev * ev;
        for (int off = 16; off >= 1; off >>= 1) n2 += __shfl_xor(n2, off, 64);
        float nrm = fmaxf(sqrtf(n2), 1e-12f);
        tbl[4096 + v * 32 + jj] = ev;
        tbl[6144 + v * 32 + jj] = ev / nrm;
    }
}

__global__ __launch_bounds__(64, 2) void build_tables(Ptrs ps, float* __restrict__ tbl,
                                                      int* __restrict__ flags)
{
    if (blockIdx.x == 0) {              // re-zero pair flags every launch
        flags[threadIdx.x] = 0;
        flags[threadIdx.x + 64] = 0;
    }
    uint32_t g0 = *(const uint32_t*)ps.p[5];
    if (g0 == 0x3F803F80u)
        build_tables_body((const __hip_bfloat16*)ps.p[0], (const __hip_bfloat16*)ps.p[1],
                          (const __hip_bfloat16*)ps.p[2], (const __hip_bfloat16*)ps.p[3],
                          (const __hip_bfloat16*)ps.p[4], (const __hip_bfloat16*)ps.p[5],
                          (const __hip_bfloat16*)ps.p[6], (const __hip_bfloat16*)ps.p[7],
                          (const __hip_bfloat16*)ps.p[8], (const __hip_bfloat16*)ps.p[9],
                          (const __hip_bfloat16*)ps.p[10], tbl);
    else
        build_tables_body((const float*)ps.p[0], (const float*)ps.p[1],
                          (const float*)ps.p[2], (const float*)ps.p[3],
                          (const float*)ps.p[4], (const float*)ps.p[5],
                          (const float*)ps.p[6], (const float*)ps.p[7],
                          (const float*)ps.p[8], (const float*)ps.p[9],
                          (const float*)ps.p[10], tbl);
}

// ---------------- Kernel 2: chunked scan, producer/consumer ---------------
// grid NB*2 (one block per (b,mat)), 512 threads = 8 waves.
// wave 0 = fold; waves 1,2,3,5,6,7 = builders; wave 4 idle (barriers only).
__global__ __launch_bounds__(512, 2) void ema_ms(
    const int* __restrict__ seq, const float* __restrict__ tbl,
    Ptrs ps, float* __restrict__ rvbuf, int* __restrict__ flags,
    void* __restrict__ outv)
{
    __shared__ float S[L_TOT];

    int bm = blockIdx.x;
    int b = bm >> 1, mat = bm & 1;
    int tid = threadIdx.x;
    int wid = tid >> 6, lane = tid & 63;
    const float bstep = BETA / 4096.0f;

    if (tid < 64) S[L_DA + tid] = 0.0f;

    // ---- prologue: stage K (into slot area), compute Graw ----------------
    const float* ktab = tbl + 2048 + mat * 4096;
    for (int i = tid; i < 2048; i += 512)
        S[(i >> 5) * 33 + (i & 31)] = ktab[i];
    __syncthreads();

    {
        float Kown[32];
#pragma unroll
        for (int j = 0; j < 32; ++j) Kown[j] = S[lane * 33 + j];
        for (int v8 = 0; v8 < 8; ++v8) {
            int vt = wid * 8 + v8;
            float acc = 0.0f;
#pragma unroll
            for (int j = 0; j < 32; ++j)
                acc = fmaf(S[vt * 33 + j], Kown[j], acc);
            S[L_GR + vt * 64 + lane] = acc;     // raw Gram (symmetric)
        }
    }
    __syncthreads();

    const int* sb = seq + (size_t)b * NL;
    float y = 0.0f;
    if (wid == 0) {
        int vlast = sb[NL - 1];
        y = S[L_GR + vlast * 64 + lane];        // y[v] = k_v . q
    }

    const int NRND = (NCH + NBLD - 1) / NBLD;   // 43 build rounds

    // ---- rounds ----------------------------------------------------------
    for (int r = 0; r <= NRND; ++r) {
        if (wid != 0 && wid != 4) {
            // ---------------- builder: V + G-rows for one chunk -----------
            int bi = (wid > 4) ? (wid - 2) : (wid - 1);   // 0..5
            int ci = NBLD * r + bi;
            if (r < NRND && ci < NCH) {
                int c = NCH - 1 - ci;
                float* slot = S + ((r & 1) * NBLD + bi) * SLOT_F;
                int tokv = 0; float bneg = 0.0f;
                if (lane < TC) {
                    int t = c * TC + (TC - 1) - lane;     // lane = step p
                    tokv = sb[t];
                    float bb = mat ? bstep * (float)(t + 1) : BETA;
                    if (t == NL - 1) bb = 0.0f;           // t=4095 pad mask
                    bneg = -bb;
                    ((int*)(slot + 1344))[lane] = tokv;
                }
                float garr[TC];                            // C_pj at lane j
#pragma unroll
                for (int p = 0; p < TC; ++p) {
                    int vp = __builtin_amdgcn_readlane(tokv, p);
                    const float* gr = S + L_GR + vp * 64;
                    slot[320 + p * 64 + lane] = gr[lane];  // grows[p][v]
                    garr[p] = gr[tokv] * bneg;             // -b_j G[v_p][v_j]
                }
                // forward substitution, column q = lane (lanes 0..15)
                float x[TC];
                x[0] = (lane == 0) ? 1.0f : 0.0f;
#pragma unroll
                for (int p = 1; p < TC; ++p) {
                    float xp = (lane == p) ? 1.0f : 0.0f;
#pragma unroll
                    for (int j = 0; j < p; ++j)
                        xp = fmaf(readlane_f(garr[p], j), x[j], xp);
                    x[p] = xp;
                }
                if (lane < TC) {
#pragma unroll
                    for (int p = 0; p < TC; ++p)
                        slot[p * 20 + lane] = x[p];        // V[p][q]
                }
            }
        } else if (wid == 0 && r >= 1) {
            // ---------------- fold wave: consume previous round -----------
            for (int bi = 0; bi < NBLD; ++bi) {
                int ci = NBLD * (r - 1) + bi;
                if (ci >= NCH) break;
                int c = NCH - 1 - ci;
                float* slot = S + (((r - 1) & 1) * NBLD + bi) * SLOT_F;
                int tokf = (lane < TC) ? ((int*)(slot + 1344))[lane] : 0;
                float bv = 0.0f;
                if (lane < TC) {
                    int t = c * TC + (TC - 1) - lane;
                    float bb = mat ? bstep * (float)(t + 1) : BETA;
                    if (t == NL - 1) bb = 0.0f;
                    bv = bb;
                }
                float ry = bperm_f(tokf << 2, y);          // ry_p = y[v_p]
                const float4* vr = (const float4*)(slot + (lane & 15) * 20);
                float4 v0 = vr[0], v1 = vr[1], v2 = vr[2], v3 = vr[3];
                float s0 = v0.x * readlane_f(ry, 0);
                float s1 = v0.y * readlane_f(ry, 1);
                float s2 = v0.z * readlane_f(ry, 2);
                float s3 = v0.w * readlane_f(ry, 3);
                s0 = fmaf(v1.x, readlane_f(ry, 4), s0);
                s1 = fmaf(v1.y, readlane_f(ry, 5), s1);
                s2 = fmaf(v1.z, readlane_f(ry, 6), s2);
                s3 = fmaf(v1.w, readlane_f(ry, 7), s3);
                s0 = fmaf(v2.x, readlane_f(ry, 8), s0);
                s1 = fmaf(v2.y, readlane_f(ry, 9), s1);
                s2 = fmaf(v2.z, readlane_f(ry, 10), s2);
                s3 = fmaf(v2.w, readlane_f(ry, 11), s3);
                s0 = fmaf(v3.x, readlane_f(ry, 12), s0);
                s1 = fmaf(v3.y, readlane_f(ry, 13), s1);
                s2 = fmaf(v3.z, readlane_f(ry, 14), s2);
                s3 = fmaf(v3.w, readlane_f(ry, 15), s3);
                float dv = ((s0 + s1) + (s2 + s3)) * bv;   // d_p = b_p s_p
                if (lane < TC) atomicAdd(&S[L_DA + tokf], dv);
                float dn = -dv;
                float ya = 0.f, yb = 0.f, yc = 0.f, yd = 0.f;
#pragma unroll
                for (int p = 0; p < TC; p += 4) {
                    ya = fmaf(readlane_f(dn, p),     slot[320 + (p)     * 64 + lane], ya);
                    yb = fmaf(readlane_f(dn, p + 1), slot[320 + (p + 1) * 64 + lane], yb);
                    yc = fmaf(readlane_f(dn, p + 2), slot[320 + (p + 2) * 64 + lane], yc);
                    yd = fmaf(readlane_f(dn, p + 3), slot[320 + (p + 3) * 64 + lane], yd);
                }
                y += (ya + yb) + (yc + yd);
            }
        }
        __syncthreads();
    }

    // ---- r-half = H^T da, publish, pair handshake ------------------------
    if (tid < 32) {
        float rr = 0.0f;
        const float* hsrc = tbl + mat * 4096;   // hs | he (unnormalized)
        for (int v = 0; v < 64; ++v)
            rr = fmaf(S[L_DA + v], hsrc[v * 32 + tid], rr);
        __hip_atomic_store(&rvbuf[bm * 32 + tid], rr,
                           __ATOMIC_RELAXED, __HIP_MEMORY_SCOPE_AGENT);
    }
    __syncthreads();
    if (tid == 0) {
        int old = __hip_atomic_fetch_add(&flags[b], 1,
                                         __ATOMIC_ACQ_REL, __HIP_MEMORY_SCOPE_AGENT);
        ((int*)S)[L_WHO] = old;
    }
    __syncthreads();
    if (((int*)S)[L_WHO] != 1) return;          // first finisher exits

    // ---- final readout for batch b (both halves now visible) -------------
    if (tid < 64)
        S[L_RV + tid] = __hip_atomic_load(&rvbuf[b * 64 + tid],
                                          __ATOMIC_RELAXED, __HIP_MEMORY_SCOPE_AGENT);
    __syncthreads();

    uint32_t g0h = *(const uint32_t*)ps.p[5];
    int isbf = (g0h == 0x3F803F80u) ? 1 : 0;
    if (tid < 64) {
        float o;
        if (isbf) {
            const __hip_bfloat16* W = (const __hip_bfloat16*)ps.p[11];
            o = __bfloat162float(((const __hip_bfloat16*)ps.p[12])[tid]);
            for (int i = 0; i < 64; ++i)
                o = fmaf(S[L_RV + i], __bfloat162float(W[i * 64 + tid]), o);
        } else {
            const float* W = (const float*)ps.p[11];
            o = ((const float*)ps.p[12])[tid];
            for (int i = 0; i < 64; ++i)
                o = fmaf(S[L_RV + i], W[i * 64 + tid], o);
        }
        S[L_O1 + tid] = o;
    }
    __syncthreads();
    if (tid < 64) {
        float o2;
        if (isbf) {
            const __hip_bfloat16* W = (const __hip_bfloat16*)ps.p[13];
            o2 = __bfloat162float(((const __hip_bfloat16*)ps.p[14])[tid]);
            for (int i = 0; i < 64; ++i)
                o2 = fmaf(S[L_O1 + i], __bfloat162float(W[i * 64 + tid]), o2);
            ((__hip_bfloat16*)outv)[b * 64 + tid] = __float2bfloat16(o2);
        } else {
            const float* W = (const float*)ps.p[13];
            o2 = ((const float*)ps.p[14])[tid];
            for (int i = 0; i < 64; ++i)
                o2 = fmaf(S[L_O1 + i], W[i * 64 + tid], o2);
            ((float*)outv)[b * 64 + tid] = o2;
        }
    }
}

extern "C" void kernel_launch(void* const* d_in, const int* in_sizes, int n_in,
                              void* d_out, int out_size, void* d_ws, size_t ws_size,
                              hipStream_t stream) {
    const int* seq = (const int*)d_in[0];
    Ptrs ps;
    for (int i = 0; i < 15; ++i) ps.p[i] = d_in[i + 1];

    // ws (floats): tbl[8192] | rvbuf[8192] | flags[128 ints]
    float* tbl = (float*)d_ws;
    float* rvbuf = tbl + 8192;
    int* flags = (int*)(rvbuf + 8192);

    build_tables<<<64, 64, 0, stream>>>(ps, tbl, flags);
    ema_ms<<<NB * 2, 512, 0, stream>>>(seq, tbl, ps, rvbuf, flags, d_out);
}